// Round 8
// baseline (503.026 us; speedup 1.0000x reference)
//
#include <hip/hip_runtime.h>
#include <hip/hip_cooperative_groups.h>
#include <math.h>

namespace cg = cooperative_groups;

#define IN_F 128
#define HID 64
#define N_NODES 100000
#define N_EDGES 1000000
#define GEMM_BLOCKS 1563 // ceil(N_NODES / 64)
#define TILES (3 * GEMM_BLOCKS)
#define LINK_BLOCKS 977  // ceil((N_EDGES/4) / 256)

typedef __attribute__((ext_vector_type(8))) short bf16x8;
typedef __attribute__((ext_vector_type(4))) float f32x4;
typedef __attribute__((ext_vector_type(4))) unsigned short u16x4;

// round-to-nearest-even fp32 -> bf16 (inputs finite)
static __device__ __forceinline__ short f2bf(float f) {
    union { float f; unsigned u; } v; v.f = f;
    unsigned r = v.u + 0x7fffu + ((v.u >> 16) & 1u);
    return (short)(r >> 16);
}
static __device__ __forceinline__ unsigned short f2bfu(float f) {
    union { float f; unsigned u; } v; v.f = f;
    unsigned r = v.u + 0x7fffu + ((v.u >> 16) & 1u);
    return (unsigned short)(r >> 16);
}
static __device__ __forceinline__ float bf2f(unsigned short u) {
    union { unsigned u; float f; } v; v.u = ((unsigned)u) << 16; return v.f;
}

// ===========================================================================
// COOPERATIVE single-kernel pipeline.
// phase0: pack W (block 0) + head4=-1 (all)          | grid.sync
// phase1: lin_att grid-strided (W staged in LDS ONCE per block, reused
//         across all strided tiles)                   | grid.sync
// phase2: link with scores (p0/q1/q2 complete now -> w rides in rec,
//         restoring the 1-load/step walk R7 broke)    | grid.sync
// phase3: 4-chain walk aggregate
// Kills: 2 launches + inter-kernel gaps (~70-100us ledger residual), K1,
//        agg's q-gather dependent chain, 2.3x W re-staging.
// ===========================================================================
__global__ __launch_bounds__(256)
void magnn_coop(const float* __restrict__ feat0, const float* __restrict__ feat1,
                const float* __restrict__ feat2,
                const int* __restrict__ e0a, const int* __restrict__ e1a,
                const int* __restrict__ e2a,
                const float* __restrict__ W, const float* __restrict__ b_feat,
                const float* __restrict__ W_att, const float* __restrict__ b_att,
                const float* __restrict__ bias,
                short* __restrict__ Wpk, float* __restrict__ H0,
                unsigned short* __restrict__ H1b, unsigned short* __restrict__ H2b,
                float* __restrict__ p0, float* __restrict__ q1, float* __restrict__ q2,
                int* __restrict__ head4, float4* __restrict__ rec,
                float* __restrict__ out)
{
    __shared__ short Wlds[8192];   // 16 KB packed W
    cg::grid_group grid = cg::this_grid();

    const int t   = threadIdx.x;
    const int bid = blockIdx.x;
    const int nb  = gridDim.x;

    // ---------------- phase 0: pack W (block 0) + init head4 ----------------
    if (bid == 0) {
        #pragma unroll
        for (int it = 0; it < 4; ++it) {
            int idx = it * 256 + t;            // entry 0..1023
            int l = idx & 63, cs = idx >> 6;
            int c = cs >> 2, s = cs & 3;
            int n = l & 15, q = l >> 4;
            short v[8];
            #pragma unroll
            for (int j = 0; j < 8; ++j)
                v[j] = f2bf(W[(32 * s + 8 * q + j) * HID + 16 * c + n]);
            *(bf16x8*)&Wpk[(size_t)idx * 8] = *(const bf16x8*)v;
        }
    }
    for (int i4 = bid * 256 + t; i4 < N_NODES; i4 += nb * 256)
        ((int4*)head4)[i4] = make_int4(-1, -1, -1, -1);

    grid.sync();

    // ---------------- stage W into LDS once per block ----------------
    #pragma unroll
    for (int it = 0; it < 4; ++it) {
        int idx = it * 256 + t;
        *(bf16x8*)&Wlds[idx * 8] = *(const bf16x8*)&Wpk[(size_t)idx * 8];
    }
    __syncthreads();

    // ---------------- phase 1: lin_att over 4689 tiles ----------------
    {
        const int wv = t >> 6;
        const int l  = t & 63;
        const int n  = l & 15;
        const int q  = l >> 4;

        for (int tile = bid; tile < TILES; tile += nb) {
            const int which = tile / GEMM_BLOCKS;
            const int gx    = tile - which * GEMM_BLOCKS;

            const float* feat = (which == 0) ? feat0 : (which == 1) ? feat1 : feat2;
            float* sOut = (which == 0) ? p0 : (which == 1) ? q1 : q2;
            unsigned short* Hb = (which == 1) ? H1b : H2b;

            const int rowBase = gx * 64 + wv * 16;
            const int gRow = rowBase + n;
            const int lr = (gRow < N_NODES) ? gRow : (N_NODES - 1);   // clamp

            // 8 independent A loads (only VMEM in the hot path)
            f32x4 X[8];
            {
                const float* ap = &feat[(size_t)lr * IN_F + 8 * q];
                #pragma unroll
                for (int ss = 0; ss < 4; ++ss) {
                    X[2 * ss]     = *(const f32x4*)(ap + 32 * ss);
                    X[2 * ss + 1] = *(const f32x4*)(ap + 32 * ss + 4);
                }
            }

            f32x4 acc[4];
            #pragma unroll
            for (int c = 0; c < 4; ++c) {
                float bv = b_feat[16 * c + n];
                acc[c][0] = bv; acc[c][1] = bv; acc[c][2] = bv; acc[c][3] = bv;
            }

            #pragma unroll
            for (int ss = 0; ss < 4; ++ss) {
                f32x4 x0 = X[2 * ss];
                f32x4 x1 = X[2 * ss + 1];
                bf16x8 a;
                a[0] = f2bf(x0[0]); a[1] = f2bf(x0[1]); a[2] = f2bf(x0[2]); a[3] = f2bf(x0[3]);
                a[4] = f2bf(x1[0]); a[5] = f2bf(x1[1]); a[6] = f2bf(x1[2]); a[7] = f2bf(x1[3]);
                #pragma unroll
                for (int c = 0; c < 4; ++c) {
                    bf16x8 bfr = *(const bf16x8*)&Wlds[((c * 4 + ss) * 64 + l) * 8];
                    acc[c] = __builtin_amdgcn_mfma_f32_16x16x32_bf16(a, bfr, acc[c], 0, 0, 0);
                }
            }

            // epilogue: store H (+ fused attention scalar)
            float part[4] = {0.f, 0.f, 0.f, 0.f};
            #pragma unroll
            for (int c = 0; c < 4; ++c) {
                int col = 16 * c + n;
                float a0 = W_att[col], a1 = W_att[HID + col];
                float ae = (which == 0) ? (a0 + a1 * (1.0f / 3.0f)) : (a1 * (1.0f / 3.0f));
                #pragma unroll
                for (int r = 0; r < 4; ++r) {
                    int row = rowBase + 4 * q + r;
                    if (row < N_NODES) {
                        if (which == 0) H0[(size_t)row * HID + col] = acc[c][r];
                        else            Hb[(size_t)row * HID + col] = f2bfu(acc[c][r]);
                    }
                    part[r] = fmaf(acc[c][r], ae, part[r]);
                }
            }
            #pragma unroll
            for (int r = 0; r < 4; ++r) {
                float p = part[r];
                p += __shfl_xor(p, 1, 64);
                p += __shfl_xor(p, 2, 64);
                p += __shfl_xor(p, 4, 64);
                p += __shfl_xor(p, 8, 64);
                int row = rowBase + 4 * q + r;
                if (n == 0 && row < N_NODES) sOut[row] = p;
            }
        }
    }

    grid.sync();

    // ---------------- phase 2: link + scores (w rides in rec) ----------------
    {
        float ba = b_att[0];
        for (int i = bid * 256 + t; i < N_EDGES / 4; i += nb * 256) {
            int4 e0v = ((const int4*)e0a)[i];
            int4 e1v = ((const int4*)e1a)[i];
            int4 e2v = ((const int4*)e2a)[i];

            float x0 = p0[e0v.x] + q1[e1v.x] + q2[e2v.x] + ba;
            float x1 = p0[e0v.y] + q1[e1v.y] + q2[e2v.y] + ba;
            float x2 = p0[e0v.z] + q1[e1v.z] + q2[e2v.z] + ba;
            float x3 = p0[e0v.w] + q1[e1v.w] + q2[e2v.w] + ba;
            // tanh in [-1,1] => exp(tanh) safe; softmax shift-invariance
            // makes skipping the segment-max exact.
            float ex0 = __expf(tanhf(x0));
            float ex1 = __expf(tanhf(x1));
            float ex2 = __expf(tanhf(x2));
            float ex3 = __expf(tanhf(x3));

            int base = i * 4;
            int old0 = atomicExch(&head4[e0v.x * 4 + 0], base + 0);
            int old1 = atomicExch(&head4[e0v.y * 4 + 1], base + 1);
            int old2 = atomicExch(&head4[e0v.z * 4 + 2], base + 2);
            int old3 = atomicExch(&head4[e0v.w * 4 + 3], base + 3);

            rec[base + 0] = make_float4(__int_as_float(e1v.x), __int_as_float(e2v.x), ex0, __int_as_float(old0));
            rec[base + 1] = make_float4(__int_as_float(e1v.y), __int_as_float(e2v.y), ex1, __int_as_float(old1));
            rec[base + 2] = make_float4(__int_as_float(e1v.z), __int_as_float(e2v.z), ex2, __int_as_float(old2));
            rec[base + 3] = make_float4(__int_as_float(e1v.w), __int_as_float(e2v.w), ex3, __int_as_float(old3));
        }
    }

    grid.sync();

    // ---------------- phase 3: 4-chain walk aggregate ----------------
    for (int g = bid * 256 + t; g < N_NODES * 16; g += nb * 256) {
        int node = g >> 4;
        int sub  = g & 15;

        int4 h4 = ((const int4*)head4)[node];
        int j0 = h4.x, j1 = h4.y, j2 = h4.z, j3 = h4.w;
        const bool hasEdges = (j0 >= 0) || (j1 >= 0) || (j2 >= 0) || (j3 >= 0);

        float denom = 0.0f;
        float ax = 0.0f, ay = 0.0f, az = 0.0f, aw = 0.0f;

        // continue while ANY chain active (AND of signs)
        while ((j0 & j1 & j2 & j3) >= 0) {
            bool a0 = j0 >= 0, a1 = j1 >= 0, a2 = j2 >= 0, a3 = j3 >= 0;
            float4 r0 = rec[a0 ? j0 : 0];
            float4 r1 = rec[a1 ? j1 : 0];
            float4 r2 = rec[a2 ? j2 : 0];
            float4 r3 = rec[a3 ? j3 : 0];

            u16x4 h10 = *(const u16x4*)&H1b[(size_t)__float_as_int(r0.x) * HID + 4 * sub];
            u16x4 h20 = *(const u16x4*)&H2b[(size_t)__float_as_int(r0.y) * HID + 4 * sub];
            u16x4 h11 = *(const u16x4*)&H1b[(size_t)__float_as_int(r1.x) * HID + 4 * sub];
            u16x4 h21 = *(const u16x4*)&H2b[(size_t)__float_as_int(r1.y) * HID + 4 * sub];
            u16x4 h12 = *(const u16x4*)&H1b[(size_t)__float_as_int(r2.x) * HID + 4 * sub];
            u16x4 h22 = *(const u16x4*)&H2b[(size_t)__float_as_int(r2.y) * HID + 4 * sub];
            u16x4 h13 = *(const u16x4*)&H1b[(size_t)__float_as_int(r3.x) * HID + 4 * sub];
            u16x4 h23 = *(const u16x4*)&H2b[(size_t)__float_as_int(r3.y) * HID + 4 * sub];

            float w0 = a0 ? r0.z : 0.0f;
            float w1 = a1 ? r1.z : 0.0f;
            float w2 = a2 ? r2.z : 0.0f;
            float w3 = a3 ? r3.z : 0.0f;

            denom += (w0 + w1) + (w2 + w3);
            ax = fmaf(w0, bf2f(h10.x) + bf2f(h20.x), ax);
            ay = fmaf(w0, bf2f(h10.y) + bf2f(h20.y), ay);
            az = fmaf(w0, bf2f(h10.z) + bf2f(h20.z), az);
            aw = fmaf(w0, bf2f(h10.w) + bf2f(h20.w), aw);
            ax = fmaf(w1, bf2f(h11.x) + bf2f(h21.x), ax);
            ay = fmaf(w1, bf2f(h11.y) + bf2f(h21.y), ay);
            az = fmaf(w1, bf2f(h11.z) + bf2f(h21.z), az);
            aw = fmaf(w1, bf2f(h11.w) + bf2f(h21.w), aw);
            ax = fmaf(w2, bf2f(h12.x) + bf2f(h22.x), ax);
            ay = fmaf(w2, bf2f(h12.y) + bf2f(h22.y), ay);
            az = fmaf(w2, bf2f(h12.z) + bf2f(h22.z), az);
            aw = fmaf(w2, bf2f(h12.w) + bf2f(h22.w), aw);
            ax = fmaf(w3, bf2f(h13.x) + bf2f(h23.x), ax);
            ay = fmaf(w3, bf2f(h13.y) + bf2f(h23.y), ay);
            az = fmaf(w3, bf2f(h13.z) + bf2f(h23.z), az);
            aw = fmaf(w3, bf2f(h13.w) + bf2f(h23.w), aw);

            j0 = a0 ? __float_as_int(r0.w) : -1;
            j1 = a1 ? __float_as_int(r1.w) : -1;
            j2 = a2 ? __float_as_int(r2.w) : -1;
            j3 = a3 ? __float_as_int(r3.w) : -1;
        }

        float4 h0v = *(const float4*)&H0[(size_t)node * HID + 4 * sub];
        float4 bv  = *(const float4*)&bias[4 * sub];
        float third = hasEdges ? (1.0f / 3.0f) : 0.0f;
        float inv   = hasEdges ? 1.0f / (3.0f * denom) : 0.0f;

        float4 o;
        o.x = bv.x + third * h0v.x + inv * ax;
        o.y = bv.y + third * h0v.y + inv * ay;
        o.z = bv.z + third * h0v.z + inv * az;
        o.w = bv.w + third * h0v.w + inv * aw;
        *(float4*)&out[(size_t)node * HID + 4 * sub] = o;
    }
}

// ===========================================================================
// FALLBACK path (only if cooperative launch is rejected): proven R7 pipeline.
// ===========================================================================
__global__ __launch_bounds__(256)
void k1_pack_init(const float* __restrict__ W, short* __restrict__ Wpk,
                  int* __restrict__ head4)
{
    int bx = blockIdx.x;
    if (bx < 4) {
        int i = bx * 256 + threadIdx.x;
        if (i < 1024) {
            int l = i & 63, cs = i >> 6;
            int c = cs >> 2, s = cs & 3;
            int n = l & 15, q = l >> 4;
            short v[8];
            #pragma unroll
            for (int j = 0; j < 8; ++j)
                v[j] = f2bf(W[(32 * s + 8 * q + j) * HID + 16 * c + n]);
            *(bf16x8*)&Wpk[(size_t)i * 8] = *(const bf16x8*)v;
        }
    } else {
        int i4 = (bx - 4) * 256 + threadIdx.x;
        if (i4 < N_NODES)
            ((int4*)head4)[i4] = make_int4(-1, -1, -1, -1);
    }
}

__global__ __launch_bounds__(256)
void k2_lin_link(const float* __restrict__ feat0, const float* __restrict__ feat1,
                 const float* __restrict__ feat2,
                 const short* __restrict__ Wpk, const float* __restrict__ b_feat,
                 const float* __restrict__ W_att,
                 float* __restrict__ H0,
                 unsigned short* __restrict__ H1b, unsigned short* __restrict__ H2b,
                 float* __restrict__ p0, float* __restrict__ q1, float* __restrict__ q2,
                 const int* __restrict__ e0a, const int* __restrict__ e1a,
                 const int* __restrict__ e2a,
                 int* __restrict__ head4, int4* __restrict__ rec)
{
    __shared__ short Wlds[8192];
    const int bx = blockIdx.x;
    const int t  = threadIdx.x;

    if (bx < LINK_BLOCKS) {
        int i = bx * 256 + t;
        if (i < N_EDGES / 4) {
            int4 e0v = ((const int4*)e0a)[i];
            int4 e1v = ((const int4*)e1a)[i];
            int4 e2v = ((const int4*)e2a)[i];
            int base = i * 4;
            int old0 = atomicExch(&head4[e0v.x * 4 + 0], base + 0);
            int old1 = atomicExch(&head4[e0v.y * 4 + 1], base + 1);
            int old2 = atomicExch(&head4[e0v.z * 4 + 2], base + 2);
            int old3 = atomicExch(&head4[e0v.w * 4 + 3], base + 3);
            rec[base + 0] = make_int4(e1v.x, e2v.x, old0, 0);
            rec[base + 1] = make_int4(e1v.y, e2v.y, old1, 0);
            rec[base + 2] = make_int4(e1v.z, e2v.z, old2, 0);
            rec[base + 3] = make_int4(e1v.w, e2v.w, old3, 0);
        }
        return;
    }

    const int gb = bx - LINK_BLOCKS;
    const int which = gb / GEMM_BLOCKS;
    const int gx    = gb % GEMM_BLOCKS;

    const float* feat = (which == 0) ? feat0 : (which == 1) ? feat1 : feat2;
    float* sOut = (which == 0) ? p0 : (which == 1) ? q1 : q2;
    unsigned short* Hb = (which == 1) ? H1b : H2b;

    const int wv = t >> 6;
    const int l  = t & 63;
    const int n  = l & 15;
    const int q  = l >> 4;
    const int rowBase = gx * 64 + wv * 16;
    const int gRow = rowBase + n;
    const int lr = (gRow < N_NODES) ? gRow : (N_NODES - 1);

    f32x4 X[8];
    {
        const float* ap = &feat[(size_t)lr * IN_F + 8 * q];
        #pragma unroll
        for (int ss = 0; ss < 4; ++ss) {
            X[2 * ss]     = *(const f32x4*)(ap + 32 * ss);
            X[2 * ss + 1] = *(const f32x4*)(ap + 32 * ss + 4);
        }
    }
    #pragma unroll
    for (int it = 0; it < 4; ++it) {
        int idx = it * 256 + t;
        *(bf16x8*)&Wlds[idx * 8] = *(const bf16x8*)&Wpk[(size_t)idx * 8];
    }
    __syncthreads();

    f32x4 acc[4];
    #pragma unroll
    for (int c = 0; c < 4; ++c) {
        float bv = b_feat[16 * c + n];
        acc[c][0] = bv; acc[c][1] = bv; acc[c][2] = bv; acc[c][3] = bv;
    }
    #pragma unroll
    for (int ss = 0; ss < 4; ++ss) {
        f32x4 x0 = X[2 * ss];
        f32x4 x1 = X[2 * ss + 1];
        bf16x8 a;
        a[0] = f2bf(x0[0]); a[1] = f2bf(x0[1]); a[2] = f2bf(x0[2]); a[3] = f2bf(x0[3]);
        a[4] = f2bf(x1[0]); a[5] = f2bf(x1[1]); a[6] = f2bf(x1[2]); a[7] = f2bf(x1[3]);
        #pragma unroll
        for (int c = 0; c < 4; ++c) {
            bf16x8 bfr = *(const bf16x8*)&Wlds[((c * 4 + ss) * 64 + l) * 8];
            acc[c] = __builtin_amdgcn_mfma_f32_16x16x32_bf16(a, bfr, acc[c], 0, 0, 0);
        }
    }
    float part[4] = {0.f, 0.f, 0.f, 0.f};
    #pragma unroll
    for (int c = 0; c < 4; ++c) {
        int col = 16 * c + n;
        float a0 = W_att[col], a1 = W_att[HID + col];
        float ae = (which == 0) ? (a0 + a1 * (1.0f / 3.0f)) : (a1 * (1.0f / 3.0f));
        #pragma unroll
        for (int r = 0; r < 4; ++r) {
            int row = rowBase + 4 * q + r;
            if (row < N_NODES) {
                if (which == 0) H0[(size_t)row * HID + col] = acc[c][r];
                else            Hb[(size_t)row * HID + col] = f2bfu(acc[c][r]);
            }
            part[r] = fmaf(acc[c][r], ae, part[r]);
        }
    }
    #pragma unroll
    for (int r = 0; r < 4; ++r) {
        float p = part[r];
        p += __shfl_xor(p, 1, 64);
        p += __shfl_xor(p, 2, 64);
        p += __shfl_xor(p, 4, 64);
        p += __shfl_xor(p, 8, 64);
        int row = rowBase + 4 * q + r;
        if (n == 0 && row < N_NODES) sOut[row] = p;
    }
}

__global__ __launch_bounds__(256)
void aggregate_mc_kernel(const int* __restrict__ head4,
                         const int4* __restrict__ rec,
                         const float* __restrict__ H0,
                         const unsigned short* __restrict__ H1b,
                         const unsigned short* __restrict__ H2b,
                         const float* __restrict__ p0, const float* __restrict__ q1,
                         const float* __restrict__ q2, const float* __restrict__ b_att,
                         const float* __restrict__ bias,
                         float* __restrict__ out)
{
    int gid  = blockIdx.x * 256 + threadIdx.x;
    int node = gid >> 4;
    int sub  = gid & 15;
    if (node >= N_NODES) return;

    int4 h4 = ((const int4*)head4)[node];
    int j0 = h4.x, j1 = h4.y, j2 = h4.z, j3 = h4.w;
    const bool hasEdges = (j0 >= 0) || (j1 >= 0) || (j2 >= 0) || (j3 >= 0);

    float pn = p0[node] + b_att[0];
    float denom = 0.0f;
    float ax = 0.0f, ay = 0.0f, az = 0.0f, aw = 0.0f;

    while ((j0 & j1 & j2 & j3) >= 0) {
        bool a0 = j0 >= 0, a1 = j1 >= 0, a2 = j2 >= 0, a3 = j3 >= 0;
        int4 r0 = rec[a0 ? j0 : 0];
        int4 r1 = rec[a1 ? j1 : 0];
        int4 r2 = rec[a2 ? j2 : 0];
        int4 r3 = rec[a3 ? j3 : 0];

        float x0 = pn + q1[r0.x] + q2[r0.y];
        float x1 = pn + q1[r1.x] + q2[r1.y];
        float x2 = pn + q1[r2.x] + q2[r2.y];
        float x3 = pn + q1[r3.x] + q2[r3.y];

        u16x4 h10 = *(const u16x4*)&H1b[(size_t)r0.x * HID + 4 * sub];
        u16x4 h20 = *(const u16x4*)&H2b[(size_t)r0.y * HID + 4 * sub];
        u16x4 h11 = *(const u16x4*)&H1b[(size_t)r1.x * HID + 4 * sub];
        u16x4 h21 = *(const u16x4*)&H2b[(size_t)r1.y * HID + 4 * sub];
        u16x4 h12 = *(const u16x4*)&H1b[(size_t)r2.x * HID + 4 * sub];
        u16x4 h22 = *(const u16x4*)&H2b[(size_t)r2.y * HID + 4 * sub];
        u16x4 h13 = *(const u16x4*)&H1b[(size_t)r3.x * HID + 4 * sub];
        u16x4 h23 = *(const u16x4*)&H2b[(size_t)r3.y * HID + 4 * sub];

        float w0 = a0 ? __expf(tanhf(x0)) : 0.0f;
        float w1 = a1 ? __expf(tanhf(x1)) : 0.0f;
        float w2 = a2 ? __expf(tanhf(x2)) : 0.0f;
        float w3 = a3 ? __expf(tanhf(x3)) : 0.0f;

        denom += (w0 + w1) + (w2 + w3);
        ax = fmaf(w0, bf2f(h10.x) + bf2f(h20.x), ax);
        ay = fmaf(w0, bf2f(h10.y) + bf2f(h20.y), ay);
        az = fmaf(w0, bf2f(h10.z) + bf2f(h20.z), az);
        aw = fmaf(w0, bf2f(h10.w) + bf2f(h20.w), aw);
        ax = fmaf(w1, bf2f(h11.x) + bf2f(h21.x), ax);
        ay = fmaf(w1, bf2f(h11.y) + bf2f(h21.y), ay);
        az = fmaf(w1, bf2f(h11.z) + bf2f(h21.z), az);
        aw = fmaf(w1, bf2f(h11.w) + bf2f(h21.w), aw);
        ax = fmaf(w2, bf2f(h12.x) + bf2f(h22.x), ax);
        ay = fmaf(w2, bf2f(h12.y) + bf2f(h22.y), ay);
        az = fmaf(w2, bf2f(h12.z) + bf2f(h22.z), az);
        aw = fmaf(w2, bf2f(h12.w) + bf2f(h22.w), aw);
        ax = fmaf(w3, bf2f(h13.x) + bf2f(h23.x), ax);
        ay = fmaf(w3, bf2f(h13.y) + bf2f(h23.y), ay);
        az = fmaf(w3, bf2f(h13.z) + bf2f(h23.z), az);
        aw = fmaf(w3, bf2f(h13.w) + bf2f(h23.w), aw);

        j0 = a0 ? r0.z : -1;
        j1 = a1 ? r1.z : -1;
        j2 = a2 ? r2.z : -1;
        j3 = a3 ? r3.z : -1;
    }

    float4 h0 = *(const float4*)&H0[(size_t)node * HID + 4 * sub];
    float4 bv = *(const float4*)&bias[4 * sub];
    float third = hasEdges ? (1.0f / 3.0f) : 0.0f;
    float inv   = hasEdges ? 1.0f / (3.0f * denom) : 0.0f;

    float4 o;
    o.x = bv.x + third * h0.x + inv * ax;
    o.y = bv.y + third * h0.y + inv * ay;
    o.z = bv.z + third * h0.z + inv * az;
    o.w = bv.w + third * h0.w + inv * aw;
    *(float4*)&out[(size_t)node * HID + 4 * sub] = o;
}

// ---------------------------------------------------------------------------
extern "C" void kernel_launch(void* const* d_in, const int* in_sizes, int n_in,
                              void* d_out, int out_size, void* d_ws, size_t ws_size,
                              hipStream_t stream)
{
    const float* feat0  = (const float*)d_in[0];
    const float* feat1  = (const float*)d_in[1];
    const float* feat2  = (const float*)d_in[2];
    const int*   edge0  = (const int*)d_in[3];
    const int*   edge1  = (const int*)d_in[4];
    const int*   edge2  = (const int*)d_in[5];
    const float* W_feat = (const float*)d_in[6];
    const float* b_feat = (const float*)d_in[7];
    const float* W_att  = (const float*)d_in[8];
    const float* b_att  = (const float*)d_in[9];
    const float* bias   = (const float*)d_in[10];
    float* out = (float*)d_out;

    // workspace layout (16B-aligned chunks first)
    float4* rec  = (float4*)d_ws;                          // 1M float4 = 16 MB
    short*  Wpk  = (short*)(rec + N_EDGES);                // 16 KB
    float*  H0   = (float*)(Wpk + 8192);                   // 25.6 MB
    unsigned short* H1b = (unsigned short*)(H0 + (size_t)N_NODES * HID); // 12.8 MB
    unsigned short* H2b = H1b + (size_t)N_NODES * HID;                   // 12.8 MB
    float*  p0   = (float*)(H2b + (size_t)N_NODES * HID);
    float*  q1   = p0 + N_NODES;
    float*  q2   = q1 + N_NODES;
    int*    head4 = (int*)(q2 + N_NODES);                  // 1.6 MB

    dim3 blk(256);

    // co-residency-safe grid size (runtime validates on launch)
    static int nblk = 0;
    if (nblk == 0) {
        int maxB = 0;
        (void)hipOccupancyMaxActiveBlocksPerMultiprocessor(&maxB, magnn_coop, 256, 0);
        if (maxB < 1) maxB = 1;
        if (maxB > 8) maxB = 8;
        nblk = maxB * 256;   // 256 CUs on MI355X
    }

    void* args[] = {
        (void*)&feat0, (void*)&feat1, (void*)&feat2,
        (void*)&edge0, (void*)&edge1, (void*)&edge2,
        (void*)&W_feat, (void*)&b_feat, (void*)&W_att, (void*)&b_att, (void*)&bias,
        (void*)&Wpk, (void*)&H0, (void*)&H1b, (void*)&H2b,
        (void*)&p0, (void*)&q1, (void*)&q2,
        (void*)&head4, (void*)&rec, (void*)&out
    };
    hipError_t err = hipLaunchCooperativeKernel((const void*)magnn_coop,
                                                dim3(nblk), blk, args, 0, stream);
    if (err == hipSuccess) return;

    // ---------------- fallback: proven R7 3-kernel pipeline ----------------
    k1_pack_init<<<4 + (N_NODES + 255) / 256, blk, 0, stream>>>(W_feat, Wpk, (int*)head4);
    k2_lin_link<<<LINK_BLOCKS + 3 * GEMM_BLOCKS, blk, 0, stream>>>(
        feat0, feat1, feat2, Wpk, b_feat, W_att,
        H0, H1b, H2b, p0, q1, q2,
        edge0, edge1, edge2, head4, (int4*)rec);
    aggregate_mc_kernel<<<((size_t)N_NODES * 16 + 255) / 256, blk, 0, stream>>>(
        head4, (const int4*)rec, H0, H1b, H2b, p0, q1, q2, b_att, bias, out);
}

// Round 9
// 334.218 us; speedup vs baseline: 1.5051x; 1.5051x over previous
//
#include <hip/hip_runtime.h>
#include <math.h>

#define IN_F 128
#define HID 64
#define N_NODES 100000
#define N_EDGES 1000000
#define GEMM_BLOCKS2 782 // ceil(N_NODES / 128)  (2 m-tiles per wave)
#define LINK_BLOCKS 977  // ceil((N_EDGES/4) / 256)

typedef __attribute__((ext_vector_type(8))) short bf16x8;
typedef __attribute__((ext_vector_type(4))) float f32x4;
typedef __attribute__((ext_vector_type(4))) unsigned short u16x4;

// round-to-nearest-even fp32 -> bf16 (inputs finite)
static __device__ __forceinline__ short f2bf(float f) {
    union { float f; unsigned u; } v; v.f = f;
    unsigned r = v.u + 0x7fffu + ((v.u >> 16) & 1u);
    return (short)(r >> 16);
}
static __device__ __forceinline__ unsigned short f2bfu(float f) {
    union { float f; unsigned u; } v; v.f = f;
    unsigned r = v.u + 0x7fffu + ((v.u >> 16) & 1u);
    return (unsigned short)(r >> 16);
}
static __device__ __forceinline__ float bf2f(unsigned short u) {
    union { unsigned u; float f; } v; v.u = ((unsigned)u) << 16; return v.f;
}
// tanh via exp: tanh(x) = 1 - 2/(e^2x + 1); exact at +-inf, ~1e-6 rel err
static __device__ __forceinline__ float fast_tanh(float x) {
    return 1.0f - 2.0f / (__expf(2.0f * x) + 1.0f);
}

// ---------------------------------------------------------------------------
// K1: pack W into bf16 B-fragment layout (blocks 0..3) ∥ head8[]=-1 init.
//   Wpk entry (c*4+s)*64 + l holds 8 bf16 = W[k][16c+n], k=32s+8q+j, l=16q+n
//   head8: 8 chain heads per node (walk critical path ~3 instead of ~5).
// ---------------------------------------------------------------------------
__global__ __launch_bounds__(256)
void k1_pack_init(const float* __restrict__ W, short* __restrict__ Wpk,
                  int* __restrict__ head8)
{
    int bx = blockIdx.x;
    if (bx < 4) {
        int i = bx * 256 + threadIdx.x;   // 1024 entries
        if (i < 1024) {
            int l = i & 63, cs = i >> 6;
            int c = cs >> 2, s = cs & 3;
            int n = l & 15, q = l >> 4;
            short v[8];
            #pragma unroll
            for (int j = 0; j < 8; ++j)
                v[j] = f2bf(W[(32 * s + 8 * q + j) * HID + 16 * c + n]);
            *(bf16x8*)&Wpk[(size_t)i * 8] = *(const bf16x8*)v;
        }
    } else {
        int i4 = (bx - 4) * 256 + threadIdx.x;     // int4 index into head8
        if (i4 < N_NODES * 2)                      // 800K ints = 200K int4
            ((int4*)head8)[i4] = make_int4(-1, -1, -1, -1);
    }
}

// ---------------------------------------------------------------------------
// K2: link (blocks 0..976) ∥ lin_att (rest) — FUSED (R7 proven).
//
// link: edge i -> chain slot i&7 of node e0:
//   old = atomicExch(&head8[e0*8 + (i&7)], i);  rec[i] = (e1, e2, next, 0)
//   rec stores sequential/coalesced.
//
// lin_att v10: 2 m-tiles per wave (128 rows/block). All 16 A-loads issued
//   before any compute -> 4KB/wave in flight (2x v7), epilogue overhead
//   amortized over 2 tiles. B from LDS (no VMEM competition, no re-sink
//   motive: total liveness ~110 VGPR < 256 budget).
//   A-frag: lane m=l&15, k=8*quad+j ; C/D: col=l&15, row=4*quad+reg [m89/m91]
// which==0 -> H0 fp32 + p0 ; which==1/2 -> H bf16 + q1/q2
// ---------------------------------------------------------------------------
__global__ __launch_bounds__(256)
void k2_lin_link(const float* __restrict__ feat0, const float* __restrict__ feat1,
                 const float* __restrict__ feat2,
                 const short* __restrict__ Wpk, const float* __restrict__ b_feat,
                 const float* __restrict__ W_att,
                 float* __restrict__ H0,
                 unsigned short* __restrict__ H1b, unsigned short* __restrict__ H2b,
                 float* __restrict__ p0, float* __restrict__ q1, float* __restrict__ q2,
                 const int* __restrict__ e0a, const int* __restrict__ e1a,
                 const int* __restrict__ e2a,
                 int* __restrict__ head8, int4* __restrict__ rec)
{
    __shared__ short Wlds[8192];   // 16 KB (lin branch only)

    const int bx = blockIdx.x;
    const int t  = threadIdx.x;

    if (bx < LINK_BLOCKS) {
        // ---------------- link branch ----------------
        int i = bx * 256 + t;
        if (i < N_EDGES / 4) {
            int4 e0v = ((const int4*)e0a)[i];
            int4 e1v = ((const int4*)e1a)[i];
            int4 e2v = ((const int4*)e2a)[i];
            int base = i * 4;
            // slot = edge_idx & 7 (uniform over random arrivals)
            int old0 = atomicExch(&head8[e0v.x * 8 + ((base + 0) & 7)], base + 0);
            int old1 = atomicExch(&head8[e0v.y * 8 + ((base + 1) & 7)], base + 1);
            int old2 = atomicExch(&head8[e0v.z * 8 + ((base + 2) & 7)], base + 2);
            int old3 = atomicExch(&head8[e0v.w * 8 + ((base + 3) & 7)], base + 3);
            rec[base + 0] = make_int4(e1v.x, e2v.x, old0, 0);
            rec[base + 1] = make_int4(e1v.y, e2v.y, old1, 0);
            rec[base + 2] = make_int4(e1v.z, e2v.z, old2, 0);
            rec[base + 3] = make_int4(e1v.w, e2v.w, old3, 0);
        }
        return;
    }

    // ---------------- lin_att branch (2 m-tiles per wave) ----------------
    const int gb = bx - LINK_BLOCKS;            // 0 .. 3*GEMM_BLOCKS2-1
    const int which = gb / GEMM_BLOCKS2;
    const int gx    = gb % GEMM_BLOCKS2;

    const float* feat = (which == 0) ? feat0 : (which == 1) ? feat1 : feat2;
    float* sOut = (which == 0) ? p0 : (which == 1) ? q1 : q2;
    unsigned short* Hb = (which == 1) ? H1b : H2b;

    const int wv = t >> 6;
    const int l  = t & 63;
    const int n  = l & 15;
    const int q  = l >> 4;
    const int rowWave = gx * 128 + wv * 32;     // this wave: rows rowWave..+31

    // --- issue ALL 16 A loads (2 tiles x 8 dwordx4) before any compute ---
    f32x4 XA[8], XB[8];
    {
        int grA = rowWave + n;
        int lrA = (grA < N_NODES) ? grA : (N_NODES - 1);
        const float* apA = &feat[(size_t)lrA * IN_F + 8 * q];
        int grB = rowWave + 16 + n;
        int lrB = (grB < N_NODES) ? grB : (N_NODES - 1);
        const float* apB = &feat[(size_t)lrB * IN_F + 8 * q];
        #pragma unroll
        for (int ss = 0; ss < 4; ++ss) {
            XA[2 * ss]     = *(const f32x4*)(apA + 32 * ss);
            XA[2 * ss + 1] = *(const f32x4*)(apA + 32 * ss + 4);
            XB[2 * ss]     = *(const f32x4*)(apB + 32 * ss);
            XB[2 * ss + 1] = *(const f32x4*)(apB + 32 * ss + 4);
        }
    }

    // --- stage W (16 KB) into LDS once per block (overlaps A-loads) ---
    #pragma unroll
    for (int it = 0; it < 4; ++it) {
        int idx = it * 256 + t;
        *(bf16x8*)&Wlds[idx * 8] = *(const bf16x8*)&Wpk[(size_t)idx * 8];
    }
    __syncthreads();

    // per-column scalars, shared by both tiles
    float bias_c[4], att_c[4];
    #pragma unroll
    for (int c = 0; c < 4; ++c) {
        int col = 16 * c + n;
        bias_c[c] = b_feat[col];
        float a0 = W_att[col], a1 = W_att[HID + col];
        att_c[c] = (which == 0) ? (a0 + a1 * (1.0f / 3.0f)) : (a1 * (1.0f / 3.0f));
    }

    #pragma unroll
    for (int mt = 0; mt < 2; ++mt) {
        f32x4 acc[4];
        #pragma unroll
        for (int c = 0; c < 4; ++c) {
            float bv = bias_c[c];
            acc[c][0] = bv; acc[c][1] = bv; acc[c][2] = bv; acc[c][3] = bv;
        }

        #pragma unroll
        for (int ss = 0; ss < 4; ++ss) {
            f32x4 x0 = (mt == 0) ? XA[2 * ss]     : XB[2 * ss];
            f32x4 x1 = (mt == 0) ? XA[2 * ss + 1] : XB[2 * ss + 1];
            bf16x8 a;
            a[0] = f2bf(x0[0]); a[1] = f2bf(x0[1]); a[2] = f2bf(x0[2]); a[3] = f2bf(x0[3]);
            a[4] = f2bf(x1[0]); a[5] = f2bf(x1[1]); a[6] = f2bf(x1[2]); a[7] = f2bf(x1[3]);
            #pragma unroll
            for (int c = 0; c < 4; ++c) {
                bf16x8 bfr = *(const bf16x8*)&Wlds[((c * 4 + ss) * 64 + l) * 8];
                acc[c] = __builtin_amdgcn_mfma_f32_16x16x32_bf16(a, bfr, acc[c], 0, 0, 0);
            }
        }

        // epilogue: store H (+ fused attention scalar)
        const int rowBase = rowWave + mt * 16;
        float part[4] = {0.f, 0.f, 0.f, 0.f};
        #pragma unroll
        for (int c = 0; c < 4; ++c) {
            int col = 16 * c + n;
            #pragma unroll
            for (int r = 0; r < 4; ++r) {
                int row = rowBase + 4 * q + r;
                if (row < N_NODES) {
                    if (which == 0) H0[(size_t)row * HID + col] = acc[c][r];
                    else            Hb[(size_t)row * HID + col] = f2bfu(acc[c][r]);
                }
                part[r] = fmaf(acc[c][r], att_c[c], part[r]);
            }
        }
        #pragma unroll
        for (int r = 0; r < 4; ++r) {
            float p = part[r];
            p += __shfl_xor(p, 1, 64);
            p += __shfl_xor(p, 2, 64);
            p += __shfl_xor(p, 4, 64);
            p += __shfl_xor(p, 8, 64);
            int row = rowBase + 4 * q + r;
            if (n == 0 && row < N_NODES) sOut[row] = p;
        }
    }
}

// ---------------------------------------------------------------------------
// Aggregate (8-chain walk): 16 lanes/node, branch-free clamped loads.
// Per iteration: 8 independent rec loads + 16 q-gathers + 16 H-row gathers
// in flight; chain critical path ~3 dependent LLC loads (vs ~5 at 4-chain).
// Scores in-walk: x = p0[n]+q1[e1]+q2[e2]+b_att; w = exp(tanh(x))
// (softmax shift-invariance, tanh bounded -> exact without segment max).
// out[n] = bias + H0[n]/3 + (1/(3*sum w)) * sum w*(H1[e1]+H2[e2])
// ---------------------------------------------------------------------------
__global__ __launch_bounds__(256)
void aggregate_mc_kernel(const int* __restrict__ head8,
                         const int4* __restrict__ rec,
                         const float* __restrict__ H0,
                         const unsigned short* __restrict__ H1b,
                         const unsigned short* __restrict__ H2b,
                         const float* __restrict__ p0, const float* __restrict__ q1,
                         const float* __restrict__ q2, const float* __restrict__ b_att,
                         const float* __restrict__ bias,
                         float* __restrict__ out)
{
    int gid  = blockIdx.x * 256 + threadIdx.x;
    int node = gid >> 4;
    int sub  = gid & 15;
    if (node >= N_NODES) return;

    int jc[8];
    {
        int4 h0v = ((const int4*)head8)[node * 2 + 0];
        int4 h1v = ((const int4*)head8)[node * 2 + 1];
        jc[0] = h0v.x; jc[1] = h0v.y; jc[2] = h0v.z; jc[3] = h0v.w;
        jc[4] = h1v.x; jc[5] = h1v.y; jc[6] = h1v.z; jc[7] = h1v.w;
    }
    // AND of signs: >=0 iff at least one chain non-negative
    int andAll = jc[0] & jc[1] & jc[2] & jc[3] & jc[4] & jc[5] & jc[6] & jc[7];
    const bool hasEdges = (andAll >= 0);

    float pn = p0[node] + b_att[0];
    float denom = 0.0f;
    float ax = 0.0f, ay = 0.0f, az = 0.0f, aw = 0.0f;

    while (andAll >= 0) {
        bool  act[8];
        int4  rr[8];
        #pragma unroll
        for (int c = 0; c < 8; ++c) {
            act[c] = jc[c] >= 0;
            rr[c]  = rec[act[c] ? jc[c] : 0];   // clamped: inactive re-read rec[0]
        }
        float xs[8];
        #pragma unroll
        for (int c = 0; c < 8; ++c)
            xs[c] = pn + q1[rr[c].x] + q2[rr[c].y];
        u16x4 h1v[8], h2v[8];
        #pragma unroll
        for (int c = 0; c < 8; ++c) {
            h1v[c] = *(const u16x4*)&H1b[(size_t)rr[c].x * HID + 4 * sub];
            h2v[c] = *(const u16x4*)&H2b[(size_t)rr[c].y * HID + 4 * sub];
        }
        #pragma unroll
        for (int c = 0; c < 8; ++c) {
            float w = act[c] ? __expf(fast_tanh(xs[c])) : 0.0f;
            denom += w;
            ax = fmaf(w, bf2f(h1v[c].x) + bf2f(h2v[c].x), ax);
            ay = fmaf(w, bf2f(h1v[c].y) + bf2f(h2v[c].y), ay);
            az = fmaf(w, bf2f(h1v[c].z) + bf2f(h2v[c].z), az);
            aw = fmaf(w, bf2f(h1v[c].w) + bf2f(h2v[c].w), aw);
            jc[c] = act[c] ? rr[c].z : -1;
        }
        andAll = jc[0] & jc[1] & jc[2] & jc[3] & jc[4] & jc[5] & jc[6] & jc[7];
    }

    float4 h0 = *(const float4*)&H0[(size_t)node * HID + 4 * sub];
    float4 bv = *(const float4*)&bias[4 * sub];
    float third = hasEdges ? (1.0f / 3.0f) : 0.0f;
    float inv   = hasEdges ? 1.0f / (3.0f * denom) : 0.0f;

    float4 o;
    o.x = bv.x + third * h0.x + inv * ax;
    o.y = bv.y + third * h0.y + inv * ay;
    o.z = bv.z + third * h0.z + inv * az;
    o.w = bv.w + third * h0.w + inv * aw;
    *(float4*)&out[(size_t)node * HID + 4 * sub] = o;
}

// ---------------------------------------------------------------------------
extern "C" void kernel_launch(void* const* d_in, const int* in_sizes, int n_in,
                              void* d_out, int out_size, void* d_ws, size_t ws_size,
                              hipStream_t stream)
{
    const float* feat0  = (const float*)d_in[0];
    const float* feat1  = (const float*)d_in[1];
    const float* feat2  = (const float*)d_in[2];
    const int*   edge0  = (const int*)d_in[3];
    const int*   edge1  = (const int*)d_in[4];
    const int*   edge2  = (const int*)d_in[5];
    const float* W_feat = (const float*)d_in[6];
    const float* b_feat = (const float*)d_in[7];
    const float* W_att  = (const float*)d_in[8];
    const float* b_att  = (const float*)d_in[9];
    const float* bias   = (const float*)d_in[10];
    float* out = (float*)d_out;

    // workspace layout (16B-aligned chunks first)
    int4*   rec  = (int4*)d_ws;                            // 1M int4 = 16 MB
    short*  Wpk  = (short*)(rec + N_EDGES);                // 16 KB
    float*  H0   = (float*)(Wpk + 8192);                   // 25.6 MB
    unsigned short* H1b = (unsigned short*)(H0 + (size_t)N_NODES * HID); // 12.8 MB
    unsigned short* H2b = H1b + (size_t)N_NODES * HID;                   // 12.8 MB
    float*  p0   = (float*)(H2b + (size_t)N_NODES * HID);
    float*  q1   = p0 + N_NODES;
    float*  q2   = q1 + N_NODES;
    int*    head8 = (int*)(q2 + N_NODES);                  // 800K ints (3.2 MB)
    // total ~74 MB

    dim3 blk(256);

    // K1: pack_w (4 blocks) ∥ head8=-1 init (782 blocks)
    k1_pack_init<<<4 + (N_NODES * 2 + 255) / 256, blk, 0, stream>>>(
        W_feat, Wpk, head8);

    // K2: link (977 blocks) ∥ fused 3x GEMM + attention partials (2346 blocks)
    k2_lin_link<<<LINK_BLOCKS + 3 * GEMM_BLOCKS2, blk, 0, stream>>>(
        feat0, feat1, feat2, Wpk, b_feat, W_att,
        H0, H1b, H2b, p0, q1, q2,
        edge0, edge1, edge2, head8, rec);

    // K3: 8-chain walk aggregation (scores computed in-walk)
    aggregate_mc_kernel<<<((size_t)N_NODES * 16 + 255) / 256, blk, 0, stream>>>(
        head8, rec, H0, H1b, H2b, p0, q1, q2, b_att, bias, out);
}